// Round 3
// baseline (3067.902 us; speedup 1.0000x reference)
//
#include <hip/hip_runtime.h>
#include <hip/hip_fp16.h>

#define S 31
#define D 14
#define H 50
#define NB 16384
#define NITER 48
#define LAMR 1e-4f

// ws float-index layout
#define WS_D2   0      // 48: global sum ||F-X||^2 per iter
#define WS_F2   64     // 48: global sum ||F||^2 per iter
#define WS_WHP  128    // 50x16 fp32 Wh (padded)
#define WS_BHX  928    // 64: bh+bx fp32
#define WS_BO   992    // 16: bo fp32
#define WS_WX2  1024   // 50x8 half2: Wx rows packed (d pairs), 400 dwords
#define WS_WO2T 1424   // 28x16 half2: Wo TRANSPOSED [hh][d], 448 dwords
#define WS_WF2  1872   // 32x8 half2: Wf per-s slices (row 31 = 0), 256 dwords
#define WS_OUTK 4096   // 48*NB floats

typedef _Float16 f16x2 __attribute__((ext_vector_type(2)));
typedef _Float16 f16x8 __attribute__((ext_vector_type(8)));

#if defined(__has_builtin) && __has_builtin(__builtin_amdgcn_rcpf)
#define FRCP(x) __builtin_amdgcn_rcpf(x)
#else
#define FRCP(x) (1.0f/(x))
#endif

#if defined(__has_builtin) && __has_builtin(__builtin_amdgcn_exp2f)
#define FEXP2(x) __builtin_amdgcn_exp2f(x)
#else
#define FEXP2(x) exp2f(x)
#endif

#define FDOT2(a,b,c) __builtin_amdgcn_fdot2((a),(b),(c),false)

__device__ __forceinline__ f16x2 pkrtz(float a, float b){
  auto r = __builtin_amdgcn_cvt_pkrtz(a, b);
  return __builtin_bit_cast(f16x2, r);
}
#define PKRTZ(a,b) pkrtz((a),(b))

__device__ __forceinline__ f16x2 pack_rn(float a, float b){
  __half2 h = __floats2half2_rn(a, b);
  return __builtin_bit_cast(f16x2, h);
}

// extract f16x2 lane j (compile-time) from f16x8
__device__ __forceinline__ f16x2 ext2(f16x8 v, int j){
  f16x2 r; r[0]=v[2*j]; r[1]=v[2*j+1]; return r;
}
#define EXT2(v,j) ext2((v),(j))

// triangular index, i<=j, 6x6
#define AIJ(i,j) ((i)*6 - ((i)*((i)+1))/2 + (j))

__device__ __forceinline__ float tfast(float x){
  // tanh(x) = 1 - 2/(exp2(x*2*log2e)+1)
  float e = FEXP2(x * 2.8853900817779268f);
  return 1.f - 2.f * FRCP(e + 1.f);
}

__global__ void prep_kernel(const float* __restrict__ Wh, const float* __restrict__ bh,
                            const float* __restrict__ Wx, const float* __restrict__ bx,
                            const float* __restrict__ Wo, const float* __restrict__ bo,
                            const float* __restrict__ Wf, float* __restrict__ ws){
  int t = threadIdx.x;                       // 1 block x 256
  for (int i=t;i<128;i+=256) ws[i]=0.f;      // zero norm accumulators
  for (int i=t;i<800;i+=256){
    int h=i>>4, d=i&15;
    ws[WS_WHP+i] = (d<D)? Wh[h*D+d] : 0.f;
  }
  for (int i=t;i<64;i+=256) ws[WS_BHX+i] = (i<H)? bh[i]+bx[i] : 0.f;
  for (int i=t;i<16;i+=256) ws[WS_BO+i]  = (i<D)? bo[i] : 0.f;
  __half2* wx2 = (__half2*)(ws + WS_WX2);
  for (int i=t;i<400;i+=256){
    int h=i>>3, dd=i&7, d0=2*dd, d1=2*dd+1;
    float a=(d0<D)?Wx[h*D+d0]:0.f, b=(d1<D)?Wx[h*D+d1]:0.f;
    wx2[i] = __floats2half2_rn(a,b);
  }
  // Wo transposed: wo2t[hh*16 + d] = (Wo[d][2hh], Wo[d][2hh+1]); hh<25, d<14 valid
  __half2* wo2t = (__half2*)(ws + WS_WO2T);
  for (int i=t;i<448;i+=256){
    int hh=i>>4, d=i&15;
    bool v = (hh<25) && (d<D);
    float a=v?Wo[d*H+2*hh]:0.f, b=v?Wo[d*H+2*hh+1]:0.f;
    wo2t[i] = __floats2half2_rn(a,b);
  }
  __half2* wf2 = (__half2*)(ws + WS_WF2);
  for (int i=t;i<256;i+=256){
    int s=i>>3, dd=i&7, d0=2*dd, d1=2*dd+1;
    float a=(s<S && d0<D)?Wf[s*D+d0]:0.f, b=(s<S && d1<D)?Wf[s*D+d1]:0.f;
    wf2[i] = __floats2half2_rn(a,b);
  }
}

// f-eval, fused layers; weights fetched as 16B f16x8 chunks (wx: 4/pair,
// wo2t: 4/pair thanks to the [hh][d] transpose). Arithmetic identical to R2.
#define FEVAL() do{ \
  float oacc_[14]; \
  _Pragma("unroll") for (int d_=0; d_<14; ++d_) oacc_[d_] = bop[d_]; \
  _Pragma("unroll") \
  for (int hh_=0; hh_<25; ++hh_){ \
    f16x2 hx2_ = hxr2[hh_]; \
    f16x8 wxa0_ = wx8[(2*hh_)*2],   wxa1_ = wx8[(2*hh_)*2+1]; \
    f16x8 wxb0_ = wx8[(2*hh_+1)*2], wxb1_ = wx8[(2*hh_+1)*2+1]; \
    float a0_ = (float)hx2_[0], b0_ = (float)hx2_[1]; \
    _Pragma("unroll") for (int q_=0;q_<4;++q_){ \
      a0_ = FDOT2(xvh[q_], EXT2(wxa0_,q_), a0_); \
      b0_ = FDOT2(xvh[q_], EXT2(wxb0_,q_), b0_); } \
    _Pragma("unroll") for (int q_=4;q_<7;++q_){ \
      a0_ = FDOT2(xvh[q_], EXT2(wxa1_,q_-4), a0_); \
      b0_ = FDOT2(xvh[q_], EXT2(wxb1_,q_-4), b0_); } \
    f16x2 th_ = PKRTZ(tfast(a0_), tfast(b0_)); \
    f16x8 woa_ = wo8[hh_*4], wob_ = wo8[hh_*4+1], woc_ = wo8[hh_*4+2], wod_ = wo8[hh_*4+3]; \
    _Pragma("unroll") for (int d_=0; d_<4; ++d_) oacc_[d_]    = FDOT2(th_, EXT2(woa_,d_), oacc_[d_]); \
    _Pragma("unroll") for (int d_=0; d_<4; ++d_) oacc_[4+d_]  = FDOT2(th_, EXT2(wob_,d_), oacc_[4+d_]); \
    _Pragma("unroll") for (int d_=0; d_<4; ++d_) oacc_[8+d_]  = FDOT2(th_, EXT2(woc_,d_), oacc_[8+d_]); \
    _Pragma("unroll") for (int d_=0; d_<2; ++d_) oacc_[12+d_] = FDOT2(th_, EXT2(wod_,d_), oacc_[12+d_]); \
  } \
  _Pragma("unroll") for (int dp_=0; dp_<7; ++dp_) \
    fvh[dp_] = PKRTZ(tfast(oacc_[2*dp_]), tfast(oacc_[2*dp_+1])); \
}while(0)

#define ZERO_INACT() do{ \
  if (!act){ \
    _Pragma("unroll") for (int q_=0;q_<7;++q_){ fvh[q_]=zzv; gvh[q_]=zzv; } \
  } \
}while(0)

// Shift-based history push (constant indices -> stays in regs).
// All 8 per-iteration 32-lane reductions batched into ONE interleaved butterfly.
#define PUSHB(DOPROJ) do{ \
  float rv_[8]; \
  _Pragma("unroll") for (int j_=0;j_<5;++j_){ \
    float acc_=0.f; \
    _Pragma("unroll") for (int q_=0;q_<7;++q_) acc_ = FDOT2(gvh[q_], Gh[(j_+1)*7+q_], acc_); \
    rv_[j_] = acc_; } \
  d2l=0.f; f2l=0.f; \
  _Pragma("unroll") for (int q_=0;q_<7;++q_){ \
    d2l = FDOT2(gvh[q_], gvh[q_], d2l); \
    f2l = FDOT2(fvh[q_], fvh[q_], f2l); } \
  rv_[5]=d2l; rv_[6]=f2l; rv_[7]=0.f; \
  if (DOPROJ){ \
    float pa_=0.f; \
    _Pragma("unroll") for (int q_=0;q_<4;++q_) pa_ = FDOT2(fvh[q_], EXT2(wfr0,q_), pa_); \
    _Pragma("unroll") for (int q_=4;q_<7;++q_) pa_ = FDOT2(fvh[q_], EXT2(wfr1,q_-4), pa_); \
    rv_[7]=pa_; } \
  _Pragma("unroll") for (int m_=1;m_<32;m_<<=1) \
    _Pragma("unroll") for (int i_=0;i_<8;++i_) rv_[i_] += __shfl_xor(rv_[i_], m_); \
  d2r = rv_[5]; f2r = rv_[6]; po_red = rv_[7]; \
  _Pragma("unroll") for (int j_=0;j_<5;++j_) \
    _Pragma("unroll") for (int q_=0;q_<7;++q_){ \
      Fh[j_*7+q_] = Fh[(j_+1)*7+q_]; Gh[j_*7+q_] = Gh[(j_+1)*7+q_]; } \
  _Pragma("unroll") for (int q_=0;q_<7;++q_){ Fh[35+q_]=fvh[q_]; Gh[35+q_]=gvh[q_]; } \
  _Pragma("unroll") for (int i_=0;i_<5;++i_) \
    _Pragma("unroll") for (int j_=i_;j_<5;++j_) GG[AIJ(i_,j_)] = GG[AIJ(i_+1,j_+1)]; \
  _Pragma("unroll") for (int j_=0;j_<5;++j_) GG[AIJ(j_,5)] = rv_[j_]; \
  GG[AIJ(5,5)] = d2r; \
}while(0)

__global__ __launch_bounds__(256, 3)
void solver_kernel(const float* __restrict__ x,
                   const float* __restrict__ whp, const float* __restrict__ bhx,
                   const float* __restrict__ bop,
                   const f16x8* __restrict__ wx8, const f16x8* __restrict__ wo8,
                   const f16x8* __restrict__ wf8,
                   float* __restrict__ outk, float* __restrict__ d2p, float* __restrict__ f2p){
  const int tid  = threadIdx.x;
  const int lane = tid & 63;
  const int s    = tid & 31;
  const int elem = blockIdx.x*8 + (tid>>5);
  const bool act = (s < S);

  // hx as f16x2, stride 27 words (odd -> all-bank spread)
  __shared__ f16x2 hx2_sh[256*27];          // 27648 B
  f16x2* hxw2 = hx2_sh + tid*27;

  { // prologue: hx[h] = x_s . Wh_h + bh_h + bx_h  (fp32, one RNE round to fp16)
    float xd[D];
#pragma unroll
    for (int d=0; d<D; ++d) xd[d]=0.f;
    if (act){
      const float* xr = x + ((size_t)elem*S + s)*D;
#pragma unroll
      for (int d=0; d<D; ++d) xd[d]=xr[d];
    }
#pragma unroll 5
    for (int hp=0; hp<25; ++hp){
      float a0 = bhx[2*hp], a1 = bhx[2*hp+1];
#pragma unroll
      for (int d=0; d<D; ++d){
        a0 += xd[d]*whp[(2*hp)*16+d];
        a1 += xd[d]*whp[(2*hp+1)*16+d];
      }
      hxw2[hp] = pack_rn(a0, a1);
    }
  }
  const f16x2* hxr2 = hxw2;
  const f16x2 zzv = {(_Float16)0.f, (_Float16)0.f};
  // per-lane Wf slice hoisted into registers (8 f16x2 = 2 f16x8)
  const f16x8 wfr0 = wf8[s*2], wfr1 = wf8[s*2+1];

  f16x2 Fh[42], Gh[42], xvh[7], fvh[7], gvh[7];
  float GG[21];
  float d2l, f2l, d2r, f2r, po_red;
#pragma unroll
  for (int i=0;i<42;++i){ Fh[i]=zzv; Gh[i]=zzv; }
#pragma unroll
  for (int i=0;i<21;++i) GG[i]=0.f;

  // init entry 0: X0=0, F0=f(0)
#pragma unroll
  for (int q=0;q<7;++q) xvh[q]=zzv;
  FEVAL();
#pragma unroll
  for (int q=0;q<7;++q) gvh[q]=fvh[q]-xvh[q];
  ZERO_INACT();
  PUSHB(0);
  // init entry 1: X1=F0, F1=f(F0)
#pragma unroll
  for (int q=0;q<7;++q) xvh[q]=fvh[q];
  FEVAL();
#pragma unroll
  for (int q=0;q<7;++q) gvh[q]=fvh[q]-xvh[q];
  ZERO_INACT();
  PUSHB(0);

#pragma unroll 1
  for (int kk=2; kk<50; ++kk){
    float A_[21], invd[6], yv[6];
    if (kk >= 6){
#pragma unroll
      for (int i=0;i<6;++i)
#pragma unroll
        for (int j=i;j<6;++j) A_[AIJ(i,j)] = GG[AIJ(i,j)] + ((i==j)?LAMR:0.f);
    } else {
      int lo = 6-kk;
#pragma unroll
      for (int i=0;i<6;++i)
#pragma unroll
        for (int j=i;j<6;++j){
          float v = GG[AIJ(i,j)] + ((i==j)?LAMR:0.f);
          A_[AIJ(i,j)] = (i>=lo)? v : ((i==j)?1e30f:0.f);
        }
    }
#pragma unroll
    for (int i=0;i<6;++i) yv[i]=1.f;
    // symmetric GE (no pivoting; SPD + big-diag pads)
#pragma unroll
    for (int p=0;p<6;++p){
      invd[p] = FRCP(A_[AIJ(p,p)]);
#pragma unroll
      for (int i=p+1;i<6;++i){
        float m = A_[AIJ(p,i)]*invd[p];
#pragma unroll
        for (int j=i;j<6;++j) A_[AIJ(i,j)] -= m*A_[AIJ(p,j)];
        yv[i] -= m*yv[p];
      }
    }
#pragma unroll
    for (int p=5;p>=0;--p){
      float acc=yv[p];
#pragma unroll
      for (int j=p+1;j<6;++j) acc -= A_[AIJ(p,j)]*yv[j];
      yv[p]=acc*invd[p];
    }
    float isum = FRCP(yv[0]+yv[1]+yv[2]+yv[3]+yv[4]+yv[5]);
    // Xk = sum_j alpha_j F_j  (fp16 packed)
#pragma unroll
    for (int q=0;q<7;++q) xvh[q]=zzv;
#pragma unroll
    for (int j=0;j<6;++j){
      _Float16 ah = (_Float16)(yv[j]*isum);
      f16x2 a2 = {ah, ah};
#pragma unroll
      for (int q=0;q<7;++q) xvh[q] += a2*Fh[j*7+q];
    }
    FEVAL();
#pragma unroll
    for (int q=0;q<7;++q) gvh[q]=fvh[q]-xvh[q];
    ZERO_INACT();
    PUSHB(1);
    float d2w = d2r + __shfl_xor(d2r, 32);
    float f2w = f2r + __shfl_xor(f2r, 32);
    if (lane==0){ atomicAdd(&d2p[kk-2], d2w); atomicAdd(&f2p[kk-2], f2w); }
    if (s==0) outk[(size_t)(kk-2)*NB + elem] = po_red;
  }
}

__global__ void final_kernel(const float* __restrict__ d2p, const float* __restrict__ f2p,
                             const float* __restrict__ outk, const float* __restrict__ bf,
                             float* __restrict__ out){
  int b = blockIdx.x*blockDim.x + threadIdx.x;
  float best = 1e8f; int kst = 0;
  for (int k=0;k<NITER;++k){
    float rel = sqrtf(d2p[k]) / (1e-5f + sqrtf(f2p[k]));
    if (rel < best){ best = rel; kst = k; }
  }
  out[b] = outk[(size_t)kst*NB + b] + bf[0];
}

extern "C" void kernel_launch(void* const* d_in, const int* in_sizes, int n_in,
                              void* d_out, int out_size, void* d_ws, size_t ws_size,
                              hipStream_t stream){
  const float* x  = (const float*)d_in[0];
  const float* Wh = (const float*)d_in[1];
  const float* bh = (const float*)d_in[2];
  const float* Wx = (const float*)d_in[3];
  const float* bx = (const float*)d_in[4];
  const float* Wo = (const float*)d_in[5];
  const float* bo = (const float*)d_in[6];
  const float* Wf = (const float*)d_in[7];
  const float* bf = (const float*)d_in[8];
  float* ws  = (float*)d_ws;
  float* out = (float*)d_out;

  hipLaunchKernelGGL(prep_kernel, dim3(1), dim3(256), 0, stream, Wh,bh,Wx,bx,Wo,bo,Wf,ws);
  hipLaunchKernelGGL(solver_kernel, dim3(NB/8), dim3(256), 0, stream,
                     x, ws+WS_WHP, ws+WS_BHX, ws+WS_BO,
                     (const f16x8*)(ws+WS_WX2), (const f16x8*)(ws+WS_WO2T),
                     (const f16x8*)(ws+WS_WF2),
                     ws+WS_OUTK, ws+WS_D2, ws+WS_F2);
  hipLaunchKernelGGL(final_kernel, dim3(NB/256), dim3(256), 0, stream,
                     ws+WS_D2, ws+WS_F2, ws+WS_OUTK, bf, out);
}